// Round 3
// baseline (825.691 us; speedup 1.0000x reference)
//
#include <hip/hip_runtime.h>
#include <hip/hip_bf16.h>

// LSTM cell: z = [x|h] @ Wstack^T + b ; gates -> c_t, h_t.
// M=4096, K=4096, N=2048 per gate x 4 gates. bf16 MFMA GEMM.
// R6: 2-barrier BM256/BH32, 2 blk/CU: 288us (MfmaUtil 43). Best so far.
// R7/R8: 1-blk/CU pipelined variants: 337/383us REGRESSION — block-TLP is the
//     effective stall-hider at this geometry; also LDS traffic (11.8GB) puts a
//     ~240us floor on any LDS-B design (85 B/cyc/CU measured b128 rate).
// R9(this): B operand bypasses LDS entirely (global->VGPR; frag layout is natural:
//     lane=h row, quad=k chunk; 16 fully-used 64B lines/wave; L1 dedups the 4
//     wm-waves sharing a frag). LDS holds only A, double-buffered (2x32KB, still
//     2 blk/CU). Stage A(t+1) issued at top of tile t -> the per-tile drain waits
//     on loads with a full tile of flight. 1 barrier/step (was 2). LDS volume
//     11.8 -> 6.3 GB. __launch_bounds__(512,4) caps regs at 128 for 16 waves/CU.

#define M_DIM 4096
#define K_DIM 4096
#define H_DIM 2048
#define BM 256
#define BH 32
#define BK 64
#define NTHREADS 512

typedef __attribute__((ext_vector_type(8))) short bf16x8;
typedef __attribute__((ext_vector_type(8))) unsigned short u16x8;
typedef __attribute__((ext_vector_type(4))) float f32x4;

__device__ __forceinline__ unsigned short f2bf(float f) {
    union { float f; unsigned int u; } v; v.f = f;
    unsigned int u = v.u;
    unsigned int r = u + 0x7FFFu + ((u >> 16) & 1u);   // round-to-nearest-even
    return (unsigned short)(r >> 16);
}

__device__ __forceinline__ float sigmoid_f(float x) {
    return 1.0f / (1.0f + __expf(-x));
}
__device__ __forceinline__ float tanh_f(float x) {
    return 2.0f / (1.0f + __expf(-2.0f * x)) - 1.0f;
}

// [rows][64] shorts: 16B chunk c of row r stored at slot (c ^ (r&7)).
__device__ __forceinline__ int sw64(int row, int koff) {
    int c  = koff >> 3;
    int sc = c ^ (row & 7);
    return row * BK + sc * 8 + (koff & 7);
}

__device__ __forceinline__ void async_load16(const unsigned short* g, unsigned short* l) {
    __builtin_amdgcn_global_load_lds(
        (const __attribute__((address_space(1))) void*)g,
        (__attribute__((address_space(3))) void*)l,
        16, 0, 0);
}

// ---------------- fp32 -> bf16 conversion prepass ----------------
__global__ __launch_bounds__(256) void convert_all(
        const float* __restrict__ x, const float* __restrict__ h,
        const float* __restrict__ Wi, const float* __restrict__ Wf,
        const float* __restrict__ Wo, const float* __restrict__ Wc,
        u16x8* __restrict__ xh_bf, u16x8* __restrict__ w_bf) {
    const int XHT = (M_DIM * K_DIM) / 8;          // 2,097,152
    int t = blockIdx.x * 256 + threadIdx.x;       // 0 .. 6,291,455
    const float* src;
    u16x8* dst;
    if (t < XHT) {
        int e = t * 8;
        int row = e >> 12;
        int col = e & 4095;
        src = (col < 2048) ? &x[(size_t)row * 2048 + col]
                           : &h[(size_t)row * 2048 + (col - 2048)];
        dst = xh_bf + t;
    } else {
        int g2 = t - XHT;                         // 0 .. 4,194,303
        long e = (long)g2 * 8;
        int row = (int)(e >> 12);                 // 0..8191
        int col = (int)(e & 4095);
        int gate = row >> 11;
        const float* Ws = (gate == 0) ? Wi : (gate == 1) ? Wf : (gate == 2) ? Wo : Wc;
        src = &Ws[(size_t)(row & 2047) * 4096 + col];
        dst = w_bf + g2;
    }
    float4 v0 = *(const float4*)src;
    float4 v1 = *(const float4*)(src + 4);
    u16x8 o;
    o[0] = f2bf(v0.x); o[1] = f2bf(v0.y); o[2] = f2bf(v0.z); o[3] = f2bf(v0.w);
    o[4] = f2bf(v1.x); o[5] = f2bf(v1.y); o[6] = f2bf(v1.z); o[7] = f2bf(v1.w);
    *dst = o;
}

// ---------------- R9: A-dbuf (LDS) + direct-global B GEMM ----------------
// grid 1024, XCD-swizzled: xcd = bid&7 owns m-rows {2xcd, 2xcd+1}.
// Block: 512 thr = 8 waves in 4m x 2h. Wave: 64m x 16h x 4 gates.
__global__ __launch_bounds__(NTHREADS, 4) void lstm_gemm_dbv(
    const unsigned short* __restrict__ xh_bf, const unsigned short* __restrict__ w_bf,
    const float* __restrict__ b_i, const float* __restrict__ b_f,
    const float* __restrict__ b_o, const float* __restrict__ b_c,
    const float* __restrict__ c_prev,
    float* __restrict__ h_out, float* __restrict__ c_out) {

    __shared__ __align__(16) unsigned short sA[2][BM * BK];   // 2 x 32KB, A only

    const int tid  = threadIdx.x;
    const int w    = tid >> 6;
    const int lane = tid & 63;
    const int l16  = lane & 15;
    const int quad = lane >> 4;
    const int wm   = w & 3;            // 4 m-groups of 64 rows
    const int wh   = w >> 2;           // 2 h-groups of 16 cols
    const int s7   = l16 & 7;

    const int bid  = blockIdx.x;       // 0..1023
    const int xcd  = bid & 7;
    const int slot = bid >> 3;         // 0..127
    const int yIdx = xcd * 2 + (slot >> 6);   // 0..15
    const int nIdx = slot & 63;               // 0..63

    const int mBase = yIdx * BM;
    const int nBase = nIdx * BH;

    f32x4 acc[4][4] = {};   // [gate][mt] : 64 regs

    // ---- A staging (DMA) addresses: linear LDS dst, pre-swizzled global src ----
    const int arowi = tid >> 3;                       // 0..63, r adds 64 rows
    const int alc   = (tid & 7) ^ (arowi & 7);        // logical chunk for slot tid&7
    const unsigned short* aS = xh_bf + (size_t)(mBase + arowi) * K_DIM + alc * 8;
    const int dmaDst = tid * 8;

    // ---- B direct-from-global fragment base (natural MFMA layout) ----
    // lane l16 -> row h = nBase + wh*16 + l16 ; quad -> k-subchunk of 8 shorts.
    const unsigned short* bvBase =
        w_bf + (size_t)(nBase + wh * 16 + l16) * K_DIM + quad * 8;

    const int aBase = (wm * 64 + l16) * BK;           // + mt*16*BK + chunk offset

    // ---- prologue: stage tile 0 into buf 0, full drain ----
#pragma unroll
    for (int r = 0; r < 4; ++r)
        async_load16(aS + (size_t)r * 64 * K_DIM, &sA[0][dmaDst + r * 4096]);
    __syncthreads();

#pragma unroll 1
    for (int t = 0; t < K_DIM / BK; ++t) {
        const unsigned short* sAc = sA[t & 1];
        unsigned short* sAn = (unsigned short*)sA[(t + 1) & 1];
        const int k0 = t * BK;

        // stage A(t+1) into the other buffer: a full tile of flight before drain
        if (t < (K_DIM / BK) - 1) {
            const unsigned short* an = aS + (size_t)(k0 + BK);
#pragma unroll
            for (int r = 0; r < 4; ++r)
                async_load16(an + (size_t)r * 64 * K_DIM, &sAn[dmaDst + r * 4096]);
        }

        // B fragments for this tile straight from global (8 x dwordx4)
        bf16x8 bv0[4], bv1[4];
#pragma unroll
        for (int g = 0; g < 4; ++g)
            bv0[g] = *(const bf16x8*)(bvBase + (size_t)g * H_DIM * K_DIM + k0);
#pragma unroll
        for (int g = 0; g < 4; ++g)
            bv1[g] = *(const bf16x8*)(bvBase + (size_t)g * H_DIM * K_DIM + k0 + 32);

        // ---- hk = 0 ----
        {
            const int co = (quad ^ s7) << 3;
            bf16x8 av[4];
#pragma unroll
            for (int mt = 0; mt < 4; ++mt)
                av[mt] = *(const bf16x8*)&sAc[aBase + mt * (16 * BK) + co];
            __builtin_amdgcn_s_setprio(1);
#pragma unroll
            for (int g = 0; g < 4; ++g)
#pragma unroll
                for (int mt = 0; mt < 4; ++mt)
                    acc[g][mt] = __builtin_amdgcn_mfma_f32_16x16x32_bf16(
                        av[mt], bv0[g], acc[g][mt], 0, 0, 0);
            __builtin_amdgcn_s_setprio(0);
        }
        // ---- hk = 1 ----
        {
            const int co = ((4 + quad) ^ s7) << 3;
            bf16x8 av[4];
#pragma unroll
            for (int mt = 0; mt < 4; ++mt)
                av[mt] = *(const bf16x8*)&sAc[aBase + mt * (16 * BK) + co];
            __builtin_amdgcn_s_setprio(1);
#pragma unroll
            for (int g = 0; g < 4; ++g)
#pragma unroll
                for (int mt = 0; mt < 4; ++mt)
                    acc[g][mt] = __builtin_amdgcn_mfma_f32_16x16x32_bf16(
                        av[mt], bv1[g], acc[g][mt], 0, 0, 0);
            __builtin_amdgcn_s_setprio(0);
        }

        // single per-tile drain: A(t+1) stage had ~the whole tile in flight;
        // bv0/bv1 already consumed (compiler-waited at first use).
        __syncthreads();
    }

    // ---- epilogue: wave-local. C/D: col=lane&15 -> n, row=quad*4+i -> m ----
    {
        const int n = nBase + wh * 16 + l16;
        const float bi = b_i[n], bff = b_f[n], bo = b_o[n], bc = b_c[n];
#pragma unroll
        for (int mt = 0; mt < 4; ++mt) {
#pragma unroll
            for (int i = 0; i < 4; ++i) {
                int m = mBase + wm * 64 + mt * 16 + quad * 4 + i;
                float zi = acc[0][mt][i] + bi;
                float zf = acc[1][mt][i] + bff;
                float zo = acc[2][mt][i] + bo;
                float zc = acc[3][mt][i] + bc;
                float ig = sigmoid_f(zi);
                float fg = sigmoid_f(zf);
                float og = sigmoid_f(zo);
                float ch = tanh_f(zc);
                size_t idx = (size_t)m * H_DIM + n;
                float c = fg * c_prev[idx] + ig * ch;
                c_out[idx] = c;
                h_out[idx] = og * tanh_f(c);
            }
        }
    }
}

// ---------------- fallback GEMM (no workspace): R6 2-barrier kernel ----------------
__global__ __launch_bounds__(NTHREADS, 2) void lstm_gemm_fb(
    const float* __restrict__ x_t, const float* __restrict__ h_t_1,
    const float* __restrict__ Wi, const float* __restrict__ Wf,
    const float* __restrict__ Wo, const float* __restrict__ Wc,
    const float* __restrict__ b_i, const float* __restrict__ b_f,
    const float* __restrict__ b_o, const float* __restrict__ b_c,
    const float* __restrict__ c_prev,
    float* __restrict__ h_out, float* __restrict__ c_out) {

    __shared__ __align__(16) unsigned short sA[BM * BK];      // [256][64] 32KB
    __shared__ __align__(16) unsigned short sB[4 * BH * BK];  // [4][32][64] 16KB

    const int tid  = threadIdx.x;
    const int w    = tid >> 6;
    const int lane = tid & 63;
    const int l16  = lane & 15;
    const int quad = lane >> 4;
    const int wm   = w & 3;
    const int wh   = w >> 2;
    const int s7   = l16 & 7;

    const int bid  = blockIdx.x;
    const int xcd  = bid & 7;
    const int slot = bid >> 3;
    const int yIdx = xcd * 2 + (slot >> 6);
    const int nIdx = slot & 63;

    const int mBase = yIdx * BM;
    const int nBase = nIdx * BH;

    f32x4 acc[4][4] = {};

    const int aBase = (wm * 64 + l16) * BK;
    const int bBase = (wh * 16 + l16) * BK;

    for (int k0 = 0; k0 < K_DIM; k0 += BK) {
        __syncthreads();
        const float* Asrc = (k0 < 2048) ? x_t : h_t_1;
        int kloc = k0 & 2047;
#pragma unroll
        for (int r = 0; r < 8; ++r) {
            int cc  = r * NTHREADS + tid;
            int row = cc >> 4;
            int ko  = (cc & 15) * 4;
            float4 v = *(const float4*)&Asrc[(size_t)(mBase + row) * 2048 + kloc + ko];
            *(ushort4*)&sA[sw64(row, ko)] =
                make_ushort4(f2bf(v.x), f2bf(v.y), f2bf(v.z), f2bf(v.w));
        }
        const float* Wg[4] = {Wi, Wf, Wo, Wc};
#pragma unroll
        for (int r = 0; r < 4; ++r) {
            int cc   = r * NTHREADS + tid;
            int gate = cc >> 9;
            int row  = (cc >> 4) & 31;
            int ko   = (cc & 15) * 4;
            float4 v = *(const float4*)&Wg[gate][(size_t)(nBase + row) * K_DIM + k0 + ko];
            *(ushort4*)&sB[gate * (BH * BK) + sw64(row, ko)] =
                make_ushort4(f2bf(v.x), f2bf(v.y), f2bf(v.z), f2bf(v.w));
        }
        __syncthreads();

#pragma unroll
        for (int hk = 0; hk < 2; ++hk) {
            const int co = ((hk * 4 + quad) ^ s7) << 3;
            bf16x8 av[4];
#pragma unroll
            for (int mt = 0; mt < 4; ++mt)
                av[mt] = *(const bf16x8*)&sA[aBase + mt * (16 * BK) + co];
            bf16x8 bv[4];
#pragma unroll
            for (int g = 0; g < 4; ++g)
                bv[g] = *(const bf16x8*)&sB[g * (BH * BK) + bBase + co];
#pragma unroll
            for (int g = 0; g < 4; ++g)
#pragma unroll
                for (int mt = 0; mt < 4; ++mt)
                    acc[g][mt] = __builtin_amdgcn_mfma_f32_16x16x32_bf16(
                        av[mt], bv[g], acc[g][mt], 0, 0, 0);
        }
    }

    {
        int n = nBase + wh * 16 + l16;
        float bi = b_i[n], bf = b_f[n], bo = b_o[n], bc = b_c[n];
#pragma unroll
        for (int mt = 0; mt < 4; ++mt) {
#pragma unroll
            for (int i = 0; i < 4; ++i) {
                int m = mBase + wm * 64 + mt * 16 + quad * 4 + i;
                float zi = acc[0][mt][i] + bi;
                float zf = acc[1][mt][i] + bf;
                float zo = acc[2][mt][i] + bo;
                float zc = acc[3][mt][i] + bc;
                float ig = sigmoid_f(zi);
                float fg = sigmoid_f(zf);
                float og = sigmoid_f(zo);
                float ch = tanh_f(zc);
                size_t idx = (size_t)m * H_DIM + n;
                float c = fg * c_prev[idx] + ig * ch;
                c_out[idx] = c;
                h_out[idx] = og * tanh_f(c);
            }
        }
    }
}

extern "C" void kernel_launch(void* const* d_in, const int* in_sizes, int n_in,
                              void* d_out, int out_size, void* d_ws, size_t ws_size,
                              hipStream_t stream) {
    const float* x_t   = (const float*)d_in[0];
    const float* h_t_1 = (const float*)d_in[1];
    const float* c_t_1 = (const float*)d_in[2];
    const float* W_i   = (const float*)d_in[3];
    const float* b_i   = (const float*)d_in[4];
    const float* W_f   = (const float*)d_in[5];
    const float* b_f   = (const float*)d_in[6];
    const float* W_o   = (const float*)d_in[7];
    const float* b_o   = (const float*)d_in[8];
    const float* W_c   = (const float*)d_in[9];
    const float* b_c   = (const float*)d_in[10];

    float* h_out = (float*)d_out;
    float* c_out = h_out + (size_t)M_DIM * H_DIM;

    dim3 grid((H_DIM / BH) * (M_DIM / BM));   // 64 * 16 = 1024, XCD-swizzled in-kernel

    const size_t need = (size_t)M_DIM * K_DIM * 2 + (size_t)4 * H_DIM * K_DIM * 2; // 96 MB
    if (ws_size >= need) {
        unsigned short* xh_bf = (unsigned short*)d_ws;
        unsigned short* w_bf  = xh_bf + (size_t)M_DIM * K_DIM;
        int total_threads = (M_DIM * K_DIM + 4 * H_DIM * K_DIM) / 8;  // 6,291,456
        convert_all<<<total_threads / 256, 256, 0, stream>>>(
            x_t, h_t_1, W_i, W_f, W_o, W_c, (u16x8*)xh_bf, (u16x8*)w_bf);
        lstm_gemm_dbv<<<grid, NTHREADS, 0, stream>>>(
            xh_bf, w_bf, b_i, b_f, b_o, b_c, c_t_1, h_out, c_out);
    } else {
        lstm_gemm_fb<<<grid, NTHREADS, 0, stream>>>(
            x_t, h_t_1, W_i, W_f, W_o, W_c,
            b_i, b_f, b_o, b_c, c_t_1, h_out, c_out);
    }
}